// Round 12
// baseline (466.515 us; speedup 1.0000x reference)
//
#include <hip/hip_runtime.h>
#include <hip/hip_bf16.h>
#include <stdint.h>
#include <stddef.h>

// ClusterLayer: q = normalize_rows( 1 / (1 + ||z-c||^2) )
// N=200000 rows, D=256, KC=256 clusters. fp32 in/out; cross-term via bf16 MFMA.
// R11: barrier-free free-running waves (de-convoy), properly resourced.
//  - NT=512, __launch_bounds__(512,1): LDS (128KB) caps at 1 block/CU anyway,
//    so each wave may use up to 256 VGPRs -> acc[16] + 4-deep ring fits
//    WITHOUT spill (R7's 1024-thr attempt died of the 64-VGPR cap; R10's
//    plain (512) capped at 128 and choked the scheduler).
//  - Each wave owns a full 16x256 tile: intra-wave row-normalize (R1-verified
//    epilogue), NO in-loop barrier, no rs exchange -> waves drift out of
//    phase and cover each other's vmem stalls.
//  - Keeps R9's 4-deep cross-tile rolling A ring + v_cvt_pk_bf16_f32.

#define NT 512
#define GRID 256
#define WAVES (GRID * 8)   // 2048 free-running waves, one tile each per sweep
#define D 256
#define KC 256

typedef __attribute__((ext_vector_type(8))) short short8;  // 8 bf16 (4 VGPRs)
typedef __attribute__((ext_vector_type(4))) float f32x4;   // MFMA accumulator

// fp32 -> bf16, round-to-nearest-even (branch-free) — prep kernels only
__device__ __forceinline__ short f2bf(float f) {
    uint32_t u = __builtin_bit_cast(uint32_t, f);
    u += 0x7FFFu + ((u >> 16) & 1u);
    return (short)(u >> 16);
}

// packed RNE f32x2 -> bf16x2 (emits v_cvt_pk_bf16_f32)
__device__ __forceinline__ unsigned int pk2(float a, float b) {
    __hip_bfloat162 h = __float22bfloat162_rn(make_float2(a, b));
    unsigned int r;
    __builtin_memcpy(&r, &h, 4);
    return r;
}

// csq[k] = ||c_k||^2 ; one wave per cluster row.
__global__ void prep_csq(const float* __restrict__ C, float* __restrict__ csq) {
    const int k = blockIdx.x;
    const int l = threadIdx.x;  // 0..63
    float4 v = *(const float4*)(C + k * D + l * 4);
    float s = v.x * v.x + v.y * v.y + v.z * v.z + v.w * v.w;
#pragma unroll
    for (int off = 32; off > 0; off >>= 1) s += __shfl_down(s, off);
    if (l == 0) csq[k] = s;
}

// Reorder C into MFMA-B fragment order, bf16 (verified R1-R10):
// Bf[((kk*16 + ct)*64 + lane)*8 + e] = bf16( C[(ct*16 + (lane&15))*D + kk*32 + (lane>>4)*8 + e] )
__global__ void prep_reorder(const float* __restrict__ C, unsigned short* __restrict__ Bf) {
    const int kk = blockIdx.x >> 4;   // 0..7
    const int ct = blockIdx.x & 15;   // 0..15
    const int lane = threadIdx.x;     // 0..63
    const int l15 = lane & 15;
    const int lg = lane >> 4;
    const float* src = C + (size_t)(ct * 16 + l15) * D + kk * 32 + lg * 8;
    float4 a0 = *(const float4*)(src);
    float4 a1 = *(const float4*)(src + 4);
    ushort4 p0, p1;
    p0.x = (unsigned short)f2bf(a0.x); p0.y = (unsigned short)f2bf(a0.y);
    p0.z = (unsigned short)f2bf(a0.z); p0.w = (unsigned short)f2bf(a0.w);
    p1.x = (unsigned short)f2bf(a1.x); p1.y = (unsigned short)f2bf(a1.y);
    p1.z = (unsigned short)f2bf(a1.z); p1.w = (unsigned short)f2bf(a1.w);
    unsigned short* dst = Bf + ((size_t)(kk * 16 + ct) * 64 + lane) * 8;
    *(ushort4*)(dst) = p0;
    *(ushort4*)(dst + 4) = p1;
}

__global__ void __launch_bounds__(NT, 1)
main_kernel(const float* __restrict__ z,
            const uint4* __restrict__ Bf,
            const float* __restrict__ csq,
            float* __restrict__ out, int ntiles) {
    __shared__ uint4 ldsB[8192];   // 128KB fragment-ordered bf16 B

    const int tid  = threadIdx.x;
    const int lane = tid & 63;
    const int wave = tid >> 6;           // 0..7
    const int l15  = lane & 15;
    const int lg   = lane >> 4;          // 0..3

    // stage whole B once (16 x dwordx4 per thread), linear -> conflict-free;
    // the ONLY barrier in the kernel.
#pragma unroll
    for (int i = 0; i < 16; ++i) ldsB[tid + i * NT] = Bf[tid + i * NT];
    __syncthreads();

    // c_sq for this lane's 16 columns (col = ct*16 + l15), kept in regs
    float csqr[16];
#pragma unroll
    for (int ct = 0; ct < 16; ++ct) csqr[ct] = csq[ct * 16 + l15];

    const char* ldsb = (const char*)ldsB;
    const int laneoff = lane << 4;

    int t = blockIdx.x * 8 + wave;       // < 2048 <= ntiles: initially valid
    const int niter = (ntiles - t + WAVES - 1) / WAVES;  // per-wave sweeps, no sync needed

    const float* zrow = z + (size_t)(t * 16 + l15) * D + lg * 8;
    // 4-deep rolling A ring: S[kk&3] holds k-step kk; refilled with kk+4.
    float4 S0[4], S1[4];
#pragma unroll
    for (int s = 0; s < 4; ++s) {
        S0[s] = *(const float4*)(zrow + s * 32);
        S1[s] = *(const float4*)(zrow + s * 32 + 4);
    }

    for (int i = 0; i < niter; ++i) {
        const int tn = t + WAVES;
        const int tnc = (tn < ntiles) ? tn : (ntiles - 1);
        const float* zrow_n = z + (size_t)(tnc * 16 + l15) * D + lg * 8;

        f32x4 acc[16];
        const f32x4 zero4 = {0.f, 0.f, 0.f, 0.f};
#pragma unroll
        for (int ct = 0; ct < 16; ++ct) acc[ct] = zero4;
        float zsq_part = 0.f;

#pragma unroll
        for (int kk = 0; kk < 8; ++kk) {
            // consume ring slot kk&3, refill with k-step kk+4
            // (kk>=4 refills from the NEXT tile's k-steps 0..3)
            float4 c0 = S0[kk & 3], c1 = S1[kk & 3];
            const float* pf = (kk < 4) ? (zrow + (kk + 4) * 32) : (zrow_n + (kk - 4) * 32);
            S0[kk & 3] = *(const float4*)(pf);
            S1[kk & 3] = *(const float4*)(pf + 4);

            zsq_part += c0.x * c0.x + c0.y * c0.y + c0.z * c0.z + c0.w * c0.w +
                        c1.x * c1.x + c1.y * c1.y + c1.z * c1.z + c1.w * c1.w;
            // packed RNE conversion: 8x v_cvt_pk_bf16_f32
            uint4 u;
            u.x = pk2(c0.x, c0.y); u.y = pk2(c0.z, c0.w);
            u.z = pk2(c1.x, c1.y); u.w = pk2(c1.z, c1.w);
            short8 af;
            __builtin_memcpy(&af, &u, 16);
#pragma unroll
            for (int ct = 0; ct < 16; ++ct) {
                // linear per-lane address -> zero bank conflicts
                short8 bf = *(const short8*)(ldsb + laneoff + ((kk * 16 + ct) << 10));
                acc[ct] = __builtin_amdgcn_mfma_f32_16x16x32_bf16(af, bf, acc[ct], 0, 0, 0);
            }
        }
        // ring now holds next tile's k-steps 0..3 (loads may still be in flight)

        // ||z_row||^2: lane holds partial for row l15; sum over the 4 lane-groups
        float zsq = zsq_part;
        zsq += __shfl_xor(zsq, 16);
        zsq += __shfl_xor(zsq, 32);
        float zsqj[4];
#pragma unroll
        for (int j = 0; j < 4; ++j) zsqj[j] = __shfl(zsq, lg * 4 + j);

        // q = 1/(1+dist); accumulate per-lane partial row sums
        float rs[4] = {0.f, 0.f, 0.f, 0.f};
#pragma unroll
        for (int ct = 0; ct < 16; ++ct) {
#pragma unroll
            for (int j = 0; j < 4; ++j) {
                float dist = zsqj[j] + csqr[ct] - 2.0f * acc[ct][j];
                dist = fmaxf(dist, 0.f);
                float qv = 1.0f / (1.0f + dist);
                acc[ct][j] = qv;
                rs[j] += qv;
            }
        }
        // reduce row sums across the 16-lane column group (intra-wave, no barrier)
#pragma unroll
        for (int j = 0; j < 4; ++j) {
            float s = rs[j];
            s += __shfl_xor(s, 1);
            s += __shfl_xor(s, 2);
            s += __shfl_xor(s, 4);
            s += __shfl_xor(s, 8);
            rs[j] = 1.0f / s;
        }
        // store: lane writes col ct*16+l15 of rows t*16 + lg*4 + j
#pragma unroll
        for (int j = 0; j < 4; ++j) {
            float* orow = out + (size_t)(t * 16 + lg * 4 + j) * KC + l15;
#pragma unroll
            for (int ct = 0; ct < 16; ++ct) orow[ct * 16] = acc[ct][j] * rs[j];
        }

        t = tn;
        zrow = zrow_n;
    }
}

extern "C" void kernel_launch(void* const* d_in, const int* in_sizes, int n_in,
                              void* d_out, int out_size, void* d_ws, size_t ws_size,
                              hipStream_t stream) {
    const float* zp = (const float*)d_in[0];
    const float* Cp = (const float*)d_in[1];
    const int N = in_sizes[0] / D;  // 200000
    unsigned short* Bf = (unsigned short*)d_ws;                          // 128KB bf16 frag-ordered
    float* csq = (float*)((char*)d_ws + (size_t)KC * D * sizeof(unsigned short));  // 1KB

    prep_csq<<<KC, 64, 0, stream>>>(Cp, csq);
    prep_reorder<<<128, 64, 0, stream>>>(Cp, Bf);

    const int ntiles = (N + 15) / 16;  // 12500
    main_kernel<<<GRID, NT, 0, stream>>>(zp, (const uint4*)Bf, csq, (float*)d_out, ntiles);
}

// Round 13
// 98.557 us; speedup vs baseline: 4.7335x; 4.7335x over previous
//
#include <hip/hip_runtime.h>
#include <hip/hip_bf16.h>
#include <stdint.h>
#include <stddef.h>

// ClusterLayer: q = normalize_rows( 1 / (1 + ||z-c||^2) )
// N=200000 rows, D=256, KC=256 clusters. fp32 in/out; cross-term via bf16 MFMA.
// R12 = R9 with the rolling A ring deepened to 8 (one FULL tile): consuming
// slot kk of tile t refills it with tile t+1's k-step kk, so issue->consume
// distance = one whole kk-loop + epilogue (~1000cyc) >= HBM latency.
// Ring = 64 VGPR; acc[8] stays AGPR-side; est ~120 arch VGPR (cap 128).
// Everything else byte-identical to R9 (101.6us, clean counters).

#define NT 512
#define GRID 256
#define PAIRS (GRID * 4)   // tile-pairs per sweep = 1024
#define D 256
#define KC 256

typedef __attribute__((ext_vector_type(8))) short short8;  // 8 bf16 (4 VGPRs)
typedef __attribute__((ext_vector_type(4))) float f32x4;   // MFMA accumulator

// fp32 -> bf16, round-to-nearest-even (branch-free) — prep kernels only
__device__ __forceinline__ short f2bf(float f) {
    uint32_t u = __builtin_bit_cast(uint32_t, f);
    u += 0x7FFFu + ((u >> 16) & 1u);
    return (short)(u >> 16);
}

// packed RNE f32x2 -> bf16x2 (emits v_cvt_pk_bf16_f32)
__device__ __forceinline__ unsigned int pk2(float a, float b) {
    __hip_bfloat162 h = __float22bfloat162_rn(make_float2(a, b));
    unsigned int r;
    __builtin_memcpy(&r, &h, 4);
    return r;
}

// csq[k] = ||c_k||^2 ; one wave per cluster row.
__global__ void prep_csq(const float* __restrict__ C, float* __restrict__ csq) {
    const int k = blockIdx.x;
    const int l = threadIdx.x;  // 0..63
    float4 v = *(const float4*)(C + k * D + l * 4);
    float s = v.x * v.x + v.y * v.y + v.z * v.z + v.w * v.w;
#pragma unroll
    for (int off = 32; off > 0; off >>= 1) s += __shfl_down(s, off);
    if (l == 0) csq[k] = s;
}

// Reorder C into MFMA-B fragment order, bf16 (verified R1-R11):
// Bf[((kk*16 + ct)*64 + lane)*8 + e] = bf16( C[(ct*16 + (lane&15))*D + kk*32 + (lane>>4)*8 + e] )
__global__ void prep_reorder(const float* __restrict__ C, unsigned short* __restrict__ Bf) {
    const int kk = blockIdx.x >> 4;   // 0..7
    const int ct = blockIdx.x & 15;   // 0..15
    const int lane = threadIdx.x;     // 0..63
    const int l15 = lane & 15;
    const int lg = lane >> 4;
    const float* src = C + (size_t)(ct * 16 + l15) * D + kk * 32 + lg * 8;
    float4 a0 = *(const float4*)(src);
    float4 a1 = *(const float4*)(src + 4);
    ushort4 p0, p1;
    p0.x = (unsigned short)f2bf(a0.x); p0.y = (unsigned short)f2bf(a0.y);
    p0.z = (unsigned short)f2bf(a0.z); p0.w = (unsigned short)f2bf(a0.w);
    p1.x = (unsigned short)f2bf(a1.x); p1.y = (unsigned short)f2bf(a1.y);
    p1.z = (unsigned short)f2bf(a1.z); p1.w = (unsigned short)f2bf(a1.w);
    unsigned short* dst = Bf + ((size_t)(kk * 16 + ct) * 64 + lane) * 8;
    *(ushort4*)(dst) = p0;
    *(ushort4*)(dst + 4) = p1;
}

__global__ void __launch_bounds__(NT)
main_kernel(const float* __restrict__ z,
            const uint4* __restrict__ Bf,
            const float* __restrict__ csq,
            float* __restrict__ out, int ntiles) {
    __shared__ uint4 ldsB[8192];                       // 128KB fragment-ordered bf16 B
    __shared__ __align__(16) float ldsRS[2][8][16];    // [parity][wave][row] row-sum exchange

    const int tid  = threadIdx.x;
    const int lane = tid & 63;
    const int wave = tid >> 6;           // 0..7
    const int l15  = lane & 15;
    const int lg   = lane >> 4;          // 0..3
    const int half = wave & 1;           // which 128-col half of the tile
    const int pair = wave >> 1;          // tile-pair index within block (0..3)

    // stage whole B once (16 x dwordx4 per thread), linear -> conflict-free
#pragma unroll
    for (int i = 0; i < 16; ++i) ldsB[tid + i * NT] = Bf[tid + i * NT];
    __syncthreads();

    // c_sq for this lane's 8 columns (col = half*128 + ct*16 + l15)
    float csqr[8];
#pragma unroll
    for (int ct = 0; ct < 8; ++ct) csqr[ct] = csq[half * 128 + ct * 16 + l15];

    const char* ldsb = (const char*)ldsB;
    const int laneoff = (lane << 4) + (half << 13);  // lane*16 + half*8 frag-blocks

    // per-block iteration count (tail-balanced)
    const int niter = (ntiles - blockIdx.x * 4 + PAIRS - 1) / PAIRS;

    int t = blockIdx.x * 4 + pair;                   // < 1024 <= ntiles: initially valid

    const float* zrow = z + (size_t)(t * 16 + l15) * D + lg * 8;
    // 8-deep rolling A ring: S[kk] holds k-step kk of the current tile;
    // consuming S[kk] refills it with the NEXT tile's k-step kk.
    float4 S0[8], S1[8];
#pragma unroll
    for (int s = 0; s < 8; ++s) {
        S0[s] = *(const float4*)(zrow + s * 32);
        S1[s] = *(const float4*)(zrow + s * 32 + 4);
    }

    for (int i = 0; i < niter; ++i) {
        const bool active = t < ntiles;
        const int tn = t + PAIRS;
        const int tnc = (tn < ntiles) ? tn : (ntiles - 1);
        const float* zrow_n = z + (size_t)(tnc * 16 + l15) * D + lg * 8;

        f32x4 acc[8];
        const f32x4 zero4 = {0.f, 0.f, 0.f, 0.f};
#pragma unroll
        for (int ct = 0; ct < 8; ++ct) acc[ct] = zero4;
        float zsq_part = 0.f;

#pragma unroll
        for (int kk = 0; kk < 8; ++kk) {
            // consume slot kk (loaded one full tile ago), refill with next tile
            float4 c0 = S0[kk], c1 = S1[kk];
            const float* pf = zrow_n + kk * 32;
            S0[kk] = *(const float4*)(pf);
            S1[kk] = *(const float4*)(pf + 4);

            zsq_part += c0.x * c0.x + c0.y * c0.y + c0.z * c0.z + c0.w * c0.w +
                        c1.x * c1.x + c1.y * c1.y + c1.z * c1.z + c1.w * c1.w;
            // packed RNE conversion: 8x v_cvt_pk_bf16_f32
            uint4 u;
            u.x = pk2(c0.x, c0.y); u.y = pk2(c0.z, c0.w);
            u.z = pk2(c1.x, c1.y); u.w = pk2(c1.z, c1.w);
            short8 af;
            __builtin_memcpy(&af, &u, 16);
#pragma unroll
            for (int ct = 0; ct < 8; ++ct) {
                // linear per-lane address -> zero bank conflicts
                short8 bf = *(const short8*)(ldsb + laneoff + ((kk * 16 + ct) << 10));
                acc[ct] = __builtin_amdgcn_mfma_f32_16x16x32_bf16(af, bf, acc[ct], 0, 0, 0);
            }
        }
        // ring now holds next tile's k-steps 0..7 (loads may still be in flight)

        // ||z_row||^2: lane holds partial for row l15; sum over the 4 lane-groups
        float zsq = zsq_part;
        zsq += __shfl_xor(zsq, 16);
        zsq += __shfl_xor(zsq, 32);
        float zsqj[4];
#pragma unroll
        for (int j = 0; j < 4; ++j) zsqj[j] = __shfl(zsq, lg * 4 + j);

        // q = 1/(1+dist); per-lane partial row sums over this wave's 8 col-frags
        float rs[4] = {0.f, 0.f, 0.f, 0.f};
#pragma unroll
        for (int ct = 0; ct < 8; ++ct) {
#pragma unroll
            for (int j = 0; j < 4; ++j) {
                float dist = zsqj[j] + csqr[ct] - 2.0f * acc[ct][j];
                dist = fmaxf(dist, 0.f);
                float qv = 1.0f / (1.0f + dist);
                acc[ct][j] = qv;
                rs[j] += qv;
            }
        }
        // reduce over the 16-lane column group -> this wave's 128-col row sums
#pragma unroll
        for (int j = 0; j < 4; ++j) {
            float s = rs[j];
            s += __shfl_xor(s, 1);
            s += __shfl_xor(s, 2);
            s += __shfl_xor(s, 4);
            s += __shfl_xor(s, 8);
            rs[j] = s;
        }
        // exchange with partner wave (other 128 cols), parity double-buffered
        if (l15 == 0) {
            float4 w = {rs[0], rs[1], rs[2], rs[3]};
            *(float4*)&ldsRS[i & 1][wave][lg * 4] = w;
        }
        asm volatile("s_waitcnt lgkmcnt(0)" ::: "memory");
        __builtin_amdgcn_s_barrier();          // raw: vmcnt NOT drained
        __builtin_amdgcn_sched_barrier(0);
        float4 prs = *(const float4*)&ldsRS[i & 1][wave ^ 1][lg * 4];
        float inv[4];
        inv[0] = 1.0f / (rs[0] + prs.x);
        inv[1] = 1.0f / (rs[1] + prs.y);
        inv[2] = 1.0f / (rs[2] + prs.z);
        inv[3] = 1.0f / (rs[3] + prs.w);

        if (active) {
#pragma unroll
            for (int j = 0; j < 4; ++j) {
                float* orow = out + (size_t)(t * 16 + lg * 4 + j) * KC + half * 128 + l15;
#pragma unroll
                for (int ct = 0; ct < 8; ++ct) orow[ct * 16] = acc[ct][j] * inv[j];
            }
        }
        t = tn;
        zrow = zrow_n;
    }
}

extern "C" void kernel_launch(void* const* d_in, const int* in_sizes, int n_in,
                              void* d_out, int out_size, void* d_ws, size_t ws_size,
                              hipStream_t stream) {
    const float* zp = (const float*)d_in[0];
    const float* Cp = (const float*)d_in[1];
    const int N = in_sizes[0] / D;  // 200000
    unsigned short* Bf = (unsigned short*)d_ws;                          // 128KB bf16 frag-ordered
    float* csq = (float*)((char*)d_ws + (size_t)KC * D * sizeof(unsigned short));  // 1KB

    prep_csq<<<KC, 64, 0, stream>>>(Cp, csq);
    prep_reorder<<<128, 64, 0, stream>>>(Cp, Bf);

    const int ntiles = (N + 15) / 16;  // 12500
    main_kernel<<<GRID, NT, 0, stream>>>(zp, (const uint4*)Bf, csq, (float*)d_out, ntiles);
}